// Round 1
// baseline (458.071 us; speedup 1.0000x reference)
//
#include <hip/hip_runtime.h>

#define D_   1024
#define B_   48
#define Q_   48
#define R_   36
#define RP_  38
#define DQ_  256
#define NPQ_ 1728   // B_*R_

typedef __attribute__((ext_vector_type(8))) short bf16x8;
typedef __attribute__((ext_vector_type(4))) float f32x4;

static __device__ __forceinline__ unsigned short f2bf(float f) {
  union { float f; unsigned u; } v; v.f = f;
  unsigned r = v.u + 0x7fffu + ((v.u >> 16) & 1u);   // round-to-nearest-even
  return (unsigned short)(r >> 16);
}
static __device__ __forceinline__ float bf2f(unsigned short h) {
  union { unsigned u; float f; } v; v.u = ((unsigned)h) << 16; return v.f;
}
static __device__ __forceinline__ void gload_lds16(const void* g, void* s) {
  __builtin_amdgcn_global_load_lds(
      (const __attribute__((address_space(1))) unsigned int*)g,
      (__attribute__((address_space(3))) unsigned int*)s, 16, 0, 0);
}

// ---------------- k_prep: cap_repr -> wdyn softmax (fp32), cap_vec ----------------
__global__ __launch_bounds__(256) void k_prep(
    const float* __restrict__ cap_embed, const float* __restrict__ Wred,
    const float* __restrict__ bred, const float* __restrict__ Wproj,
    const float* __restrict__ bproj, float* __restrict__ wpl,
    float* __restrict__ capvec)
{
  const int q = blockIdx.x, t = threadIdx.x;
  __shared__ __align__(16) float cap0[D_];
  __shared__ __align__(16) float repr[DQ_];
  __shared__ __align__(16) float logits[3072];
  __shared__ float red[4];

  float4 v = ((const float4*)(cap_embed + (size_t)q * 32 * D_))[t];  // token 0
  ((float4*)cap0)[t] = v;
  float ss = v.x*v.x + v.y*v.y + v.z*v.z + v.w*v.w;
  #pragma unroll
  for (int off = 32; off > 0; off >>= 1) ss += __shfl_down(ss, off);
  if ((t & 63) == 0) red[t >> 6] = ss;
  __syncthreads();
  float rinv = rsqrtf(red[0] + red[1] + red[2] + red[3]);
  float4 cv; cv.x = v.x*rinv; cv.y = v.y*rinv; cv.z = v.z*rinv; cv.w = v.w*rinv;
  ((float4*)(capvec + (size_t)q * D_))[t] = cv;

  {   // cap_repr[t] = Wred[t,:] . cap0 + bred[t]
    const float4* wr = (const float4*)(Wred + (size_t)t * D_);
    const float4* c4 = (const float4*)cap0;
    float acc = bred[t];
    for (int i = 0; i < 256; i++) {
      float4 w4 = wr[i], x4 = c4[i];
      acc += w4.x*x4.x + w4.y*x4.y + w4.z*x4.z + w4.w*x4.w;
    }
    repr[t] = acc;
  }
  __syncthreads();
  for (int jj = 0; jj < 12; jj++) {  // 3072 logits
    int j = jj * 256 + t;
    const float4* wp = (const float4*)(Wproj + (size_t)j * DQ_);
    const float4* r4 = (const float4*)repr;
    float acc = bproj[j];
    for (int i = 0; i < 64; i++) {
      float4 w4 = wp[i], x4 = r4[i];
      acc += w4.x*x4.x + w4.y*x4.y + w4.z*x4.z + w4.w*x4.w;
    }
    logits[j] = acc;
  }
  __syncthreads();
  #pragma unroll
  for (int ii = 0; ii < 4; ii++) {   // softmax over K=3, store planes [q][k][c]
    int d = t * 4 + ii;
    float l0 = logits[d*3], l1 = logits[d*3+1], l2 = logits[d*3+2];
    float m = fmaxf(l0, fmaxf(l1, l2));
    float e0 = expf(l0-m), e1 = expf(l1-m), e2 = expf(l2-m);
    float inv = 1.0f / (e0 + e1 + e2);
    wpl[((size_t)q*3 + 0) * D_ + d] = e0 * inv;
    wpl[((size_t)q*3 + 1) * D_ + d] = e1 * inv;
    wpl[((size_t)q*3 + 2) * D_ + d] = e2 * inv;
  }
}

// ---------------- k_xpad: img_embed -> bf16, layout [b][rp][c], rp zero-padded ----------------
__global__ __launch_bounds__(256) void k_xpad(const float* __restrict__ img,
                                              unsigned short* __restrict__ xpb)
{
  const int br = blockIdx.x;            // 0..48*38-1
  const int b = br / RP_, rp = br % RP_;
  const int c = threadIdx.x * 4;
  short4 o;
  if (rp == 0 || rp == RP_ - 1) { o.x = 0; o.y = 0; o.z = 0; o.w = 0; }
  else {
    float4 v = *(const float4*)&img[((size_t)b * R_ + (rp-1)) * D_ + c];
    o.x = (short)f2bf(v.x); o.y = (short)f2bf(v.y);
    o.z = (short)f2bf(v.z); o.w = (short)f2bf(v.w);
  }
  *(short4*)&xpb[(size_t)br * D_ + c] = o;
}

// ---------------- k_wcbf: Wconv fp32 -> bf16 ----------------
__global__ __launch_bounds__(256) void k_wcbf(const float* __restrict__ Wconv,
                                              unsigned short* __restrict__ wcbf)
{
  const size_t idx = ((size_t)blockIdx.x * 256 + threadIdx.x) * 4;
  float4 v = *(const float4*)&Wconv[idx];
  short4 o;
  o.x = (short)f2bf(v.x); o.y = (short)f2bf(v.y);
  o.z = (short)f2bf(v.z); o.w = (short)f2bf(v.w);
  *(short4*)&wcbf[idx] = o;
}

// ---------------- k_cd: conv_dyn bf16, layout [ql][n=b*36+r][c] (B^T for GEMM) ----------------
__global__ __launch_bounds__(256) void k_cd(const unsigned short* __restrict__ xpb,
    const float* __restrict__ wpl, unsigned short* __restrict__ cd, int qstart)
{
  const int b = blockIdx.x, ql = blockIdx.y, qg = qstart + ql;
  const int cb = threadIdx.x * 4;
  float w0[4], w1[4], w2[4];
  #pragma unroll
  for (int i = 0; i < 4; i++) {
    w0[i] = wpl[((size_t)qg*3 + 0)*D_ + cb + i];
    w1[i] = wpl[((size_t)qg*3 + 1)*D_ + cb + i];
    w2[i] = wpl[((size_t)qg*3 + 2)*D_ + cb + i];
  }
  const unsigned short* xb = xpb + (size_t)b * RP_ * D_ + cb;
  union S4 { short4 v; short a[4]; };
  S4 ra, rb, rc, o;
  ra.v = *(const short4*)&xb[0];
  rb.v = *(const short4*)&xb[D_];
  unsigned short* outp = cd + ((size_t)ql * NPQ_ + (size_t)b * R_) * D_ + cb;
  for (int r = 0; r < R_; r++) {
    rc.v = *(const short4*)&xb[(size_t)(r + 2) * D_];
    #pragma unroll
    for (int i = 0; i < 4; i++) {
      float y = w0[i]*bf2f((unsigned short)ra.a[i])
              + w1[i]*bf2f((unsigned short)rb.a[i])
              + w2[i]*bf2f((unsigned short)rc.a[i]);
      o.a[i] = (short)f2bf(y);
    }
    *(short4*)&outp[(size_t)r * D_] = o.v;
    ra = rb; rb = rc;
  }
}

// ---------------- k_gemm: Y = Wconv @ Cd_q, fused r-softmax epilogue -> imgvec ----------------
#define BM_ 128
#define BN_ 144
#define BK_ 32

__global__ __launch_bounds__(256, 2) void k_gemm(
    const unsigned short* __restrict__ wcbf, const unsigned short* __restrict__ cd,
    const float* __restrict__ bconv, float* __restrict__ imgvec, int qstart)
{
  __shared__ __align__(16) unsigned char smem[37376];   // max(A 8KB + B 9KB, ep 128*73*4)
  unsigned short* As = (unsigned short*)smem;            // [128][32] bf16
  unsigned short* Bs = (unsigned short*)(smem + 8192);   // [144][32] bf16
  float* ep = (float*)smem;                              // [128][73] fp32 (epilogue)

  const int t = threadIdx.x;
  const int w = t >> 6, lane = t & 63;
  const int nt0 = blockIdx.x * BN_;
  const int dt0 = blockIdx.y * BM_;
  const int ql = blockIdx.z, qg = qstart + ql;

  f32x4 acc[2][9];
  #pragma unroll
  for (int mm = 0; mm < 2; mm++)
    #pragma unroll
    for (int nt = 0; nt < 9; nt++)
      acc[mm][nt] = (f32x4){0.f, 0.f, 0.f, 0.f};

  const int lrow = lane >> 2;          // 0..15 (row within 16-row chunk)
  const int lc8  = (lane & 3) * 8;     // 0,8,16,24 (k offset)
  const unsigned short* Ag = wcbf + (size_t)dt0 * D_ + lc8;
  const unsigned short* Bg = cd + ((size_t)ql * NPQ_ + nt0) * D_ + lc8;
  const int fr = lane & 15, fk = (lane >> 4) * 8;

  for (int k0 = 0; k0 < D_; k0 += BK_) {
    #pragma unroll
    for (int jj = 0; jj < 2; jj++) {           // A: 8 chunks of 16 rows
      int j = w + jj * 4;
      gload_lds16(Ag + (size_t)(j*16 + lrow) * D_ + k0, As + j * 512);
    }
    for (int j = w; j < 9; j += 4) {           // B: 9 chunks of 16 rows
      gload_lds16(Bg + (size_t)(j*16 + lrow) * D_ + k0, Bs + j * 512);
    }
    __syncthreads();
    bf16x8 aF[2], bF[9];
    #pragma unroll
    for (int mm = 0; mm < 2; mm++)
      aF[mm] = *(const bf16x8*)&As[(w*32 + mm*16 + fr) * 32 + fk];
    #pragma unroll
    for (int nt = 0; nt < 9; nt++)
      bF[nt] = *(const bf16x8*)&Bs[(nt*16 + fr) * 32 + fk];
    #pragma unroll
    for (int mm = 0; mm < 2; mm++)
      #pragma unroll
      for (int nt = 0; nt < 9; nt++)
        acc[mm][nt] = __builtin_amdgcn_mfma_f32_16x16x32_bf16(aF[mm], bF[nt], acc[mm][nt], 0, 0, 0);
    __syncthreads();
  }

  // Epilogue: softmax over r (36 cols per b), two 72-col passes, ep pitch 73.
  const int quad = lane >> 4;
  const int b0 = nt0 / R_;   // first image-batch index of this tile (4 b's per tile)
  #pragma unroll
  for (int p = 0; p < 2; p++) {
    #pragma unroll
    for (int mm = 0; mm < 2; mm++)
      #pragma unroll
      for (int nt = 0; nt < 9; nt++) {
        int col = nt * 16 + fr;
        int cl = col - 72 * p;
        if (cl >= 0 && cl < 72) {
          #pragma unroll
          for (int rg = 0; rg < 4; rg++) {
            int row = w * 32 + mm * 16 + quad * 4 + rg;
            ep[row * 73 + cl] = acc[mm][nt][rg];
          }
        }
      }
    __syncthreads();
    {
      int dloc = t >> 1, bloc = t & 1;
      int bg = b0 + p * 2 + bloc;
      const float* yr = ep + dloc * 73 + bloc * 36;
      float m = yr[0];
      for (int r = 1; r < R_; r++) m = fmaxf(m, yr[r]);
      float s = 0.f, wsum = 0.f;
      for (int r = 0; r < R_; r++) {
        float yv = yr[r];
        float e = __expf(yv - m);
        s += e; wsum += e * yv;
      }
      // bconv[d] is constant over r: softmax mask unchanged, add after weighted sum
      float img = wsum / s + bconv[dt0 + dloc];
      imgvec[((size_t)qg * B_ + bg) * D_ + dt0 + dloc] = img;
    }
    __syncthreads();
  }
}

// ---------------- k_sims: l2norm + dot -> out[b][q] ----------------
__global__ __launch_bounds__(256) void k_sims(const float* __restrict__ imgvec,
    const float* __restrict__ capvec, float* __restrict__ out)
{
  const int q = blockIdx.x, b = blockIdx.y, t = threadIdx.x;
  const float4* iv = (const float4*)(imgvec + ((size_t)q * B_ + b) * D_);
  const float4* cv = (const float4*)(capvec + (size_t)q * D_);
  float4 a = iv[t], c = cv[t];
  float ss = a.x*a.x + a.y*a.y + a.z*a.z + a.w*a.w;
  float dt = a.x*c.x + a.y*c.y + a.z*c.z + a.w*c.w;
  #pragma unroll
  for (int off = 32; off > 0; off >>= 1) {
    ss += __shfl_down(ss, off);
    dt += __shfl_down(dt, off);
  }
  __shared__ float r1[4], r2[4];
  if ((t & 63) == 0) { r1[t >> 6] = ss; r2[t >> 6] = dt; }
  __syncthreads();
  if (t == 0) {
    ss = r1[0] + r1[1] + r1[2] + r1[3];
    dt = r2[0] + r2[1] + r2[2] + r2[3];
    out[(size_t)b * Q_ + q] = dt * rsqrtf(ss);
  }
}

extern "C" void kernel_launch(void* const* d_in, const int* in_sizes, int n_in,
                              void* d_out, int out_size, void* d_ws, size_t ws_size,
                              hipStream_t stream)
{
  (void)in_sizes; (void)n_in; (void)out_size;
  const float* img   = (const float*)d_in[0];
  const float* cap   = (const float*)d_in[1];
  // d_in[2] = lens : unused by the reference
  const float* Wred  = (const float*)d_in[3];
  const float* bred  = (const float*)d_in[4];
  const float* Wproj = (const float*)d_in[5];
  const float* bproj = (const float*)d_in[6];
  const float* Wconv = (const float*)d_in[7];
  const float* bconv = (const float*)d_in[8];
  float* out = (float*)d_out;

  char* ws = (char*)d_ws;
  const size_t XPB_B  = (size_t)B_ * RP_ * D_ * 2;       // 3,735,552
  const size_t WCBF_B = (size_t)D_ * D_ * 2;             // 2,097,152
  const size_t WPL_B  = (size_t)Q_ * 3 * D_ * 4;         //   589,824
  const size_t CAPV_B = (size_t)Q_ * D_ * 4;             //   196,608
  const size_t IMGV_B = (size_t)Q_ * B_ * D_ * 4;        // 9,437,184
  unsigned short* xpb  = (unsigned short*)ws;
  unsigned short* wcbf = (unsigned short*)(ws + XPB_B);
  float* wpl    = (float*)(ws + XPB_B + WCBF_B);
  float* capvec = (float*)(ws + XPB_B + WCBF_B + WPL_B);
  float* imgvec = (float*)(ws + XPB_B + WCBF_B + WPL_B + CAPV_B);
  const size_t FIXED = XPB_B + WCBF_B + WPL_B + CAPV_B + IMGV_B;  // 16,056,320
  unsigned short* cdbuf = (unsigned short*)(ws + FIXED);
  const size_t PERQ = (size_t)NPQ_ * D_ * 2;             // 3,538,944 per q

  int qchunk = 1;
  if (ws_size > FIXED + PERQ) {
    size_t c = (ws_size - FIXED) / PERQ;
    qchunk = (c > (size_t)Q_) ? Q_ : (int)c;
  }

  k_prep<<<dim3(Q_), dim3(256), 0, stream>>>(cap, Wred, bred, Wproj, bproj, wpl, capvec);
  k_xpad<<<dim3(B_ * RP_), dim3(256), 0, stream>>>(img, xpb);
  k_wcbf<<<dim3(D_ * D_ / 1024), dim3(256), 0, stream>>>(Wconv, wcbf);
  for (int q0 = 0; q0 < Q_; q0 += qchunk) {
    int qs = (Q_ - q0 < qchunk) ? (Q_ - q0) : qchunk;
    k_cd<<<dim3(B_, qs), dim3(256), 0, stream>>>(xpb, wpl, cdbuf, q0);
    k_gemm<<<dim3(NPQ_ / BN_, D_ / BM_, qs), dim3(256), 0, stream>>>(wcbf, cdbuf, bconv, imgvec, q0);
  }
  k_sims<<<dim3(Q_, B_), dim3(256), 0, stream>>>(imgvec, capvec, out);
}